// Round 1
// baseline (509.387 us; speedup 1.0000x reference)
//
#include <hip/hip_runtime.h>
#include <hip/hip_bf16.h>

// meshLayer: out[n] = sum_{e: row[e]==n} sum_k ff[e,k] * (x[col[e]] @ W[k])
// Factored as: AGG[n, k*64+ci] = sum_e ff[e,k]*x[col[e],ci]  (CSR + per-node wave)
// then        out = AGG[N x 576] @ W[576 x 64]               (bf16 MFMA GEMM)

#define CH 64
#define KB 9

using f32x4  = __attribute__((ext_vector_type(4))) float;
using bf16x8 = __attribute__((ext_vector_type(8))) short;

__device__ __forceinline__ float bf2f(unsigned short u) {
    unsigned v = ((unsigned)u) << 16;
    return __builtin_bit_cast(float, v);
}
__device__ __forceinline__ unsigned short f2bf(float f) {
    unsigned x = __builtin_bit_cast(unsigned, f);
    unsigned r = (x + 0x7FFFu + ((x >> 16) & 1u)) >> 16;   // round-nearest-even
    return (unsigned short)r;
}

// ---------------- phase 1: CSR build ----------------

__global__ void k_hist(const int* __restrict__ row, int* __restrict__ cnt, int E, int Nn) {
    int stride = gridDim.x * blockDim.x;
    for (int e = blockIdx.x * blockDim.x + threadIdx.x; e < E; e += stride) {
        int r = row[e];
        r = (r < 0) ? 0 : ((r >= Nn) ? Nn - 1 : r);
        atomicAdd(&cnt[r], 1);
    }
}

// per-256-chunk exclusive scan; writes chunk totals
__global__ void k_scan1(const int* __restrict__ cnt, int* __restrict__ loc,
                        int* __restrict__ csum, int Nn) {
    int t = threadIdx.x, lane = t & 63, w = t >> 6;
    int i = blockIdx.x * 256 + t;
    int v = (i < Nn) ? cnt[i] : 0;
    int x = v;
#pragma unroll
    for (int off = 1; off < 64; off <<= 1) {
        int y = __shfl_up(x, off);
        if (lane >= off) x += y;
    }
    __shared__ int ws[4], wo[4];
    if (lane == 63) ws[w] = x;
    __syncthreads();
    if (t == 0) {
        int s = 0;
        for (int j = 0; j < 4; j++) { int tv = ws[j]; wo[j] = s; s += tv; }
    }
    __syncthreads();
    x += wo[w];
    if (i < Nn) loc[i] = x - v;          // exclusive within chunk
    if (t == 255) csum[blockIdx.x] = x;  // chunk total
}

// single block: exclusive scan of <=256 chunk totals
__global__ void k_scan2(const int* __restrict__ csum, int* __restrict__ coff, int nch) {
    int t = threadIdx.x, lane = t & 63, w = t >> 6;
    int v = (t < nch) ? csum[t] : 0;
    int x = v;
#pragma unroll
    for (int off = 1; off < 64; off <<= 1) {
        int y = __shfl_up(x, off);
        if (lane >= off) x += y;
    }
    __shared__ int ws[4], wo[4];
    if (lane == 63) ws[w] = x;
    __syncthreads();
    if (t == 0) {
        int s = 0;
        for (int j = 0; j < 4; j++) { int tv = ws[j]; wo[j] = s; s += tv; }
    }
    __syncthreads();
    x += wo[w];
    if (t < nch) coff[t] = x - v;
}

__global__ void k_scan3(const int* __restrict__ loc, const int* __restrict__ coff,
                        int* __restrict__ starts, int* __restrict__ cur, int Nn, int E) {
    int i = blockIdx.x * 256 + threadIdx.x;
    if (i < Nn) {
        int st = loc[i] + coff[i >> 8];
        starts[i] = st;
        cur[i] = st;
    }
    if (i == 0) starts[Nn] = E;
}

__global__ void k_scatter(const int* __restrict__ row, int* __restrict__ cur,
                          int* __restrict__ sorted, int E, int Nn) {
    int stride = gridDim.x * blockDim.x;
    for (int e = blockIdx.x * blockDim.x + threadIdx.x; e < E; e += stride) {
        int r = row[e];
        r = (r < 0) ? 0 : ((r >= Nn) ? Nn - 1 : r);
        int pos = atomicAdd(&cur[r], 1);
        sorted[pos] = e;
    }
}

// ---------------- phase 2: dtype prep ----------------

__global__ void k_xconv(const float* __restrict__ x, unsigned short* __restrict__ xb, int n) {
    int stride = gridDim.x * blockDim.x;
    for (int i = blockIdx.x * blockDim.x + threadIdx.x; i < n; i += stride)
        xb[i] = f2bf(x[i]);
}

// W[q=k*64+ci][co] -> B-fragment layout for mfma_f32_16x16x32_bf16
// frag f = kstep*4 + colblk ; lane holds B[kstep*32 + (lane>>4)*8 + j][colblk*16 + (lane&15)]
__global__ void k_wprep(const float* __restrict__ W, unsigned short* __restrict__ wf) {
    int tid = blockIdx.x * 256 + threadIdx.x;
    if (tid >= 72 * 64) return;
    int f = tid >> 6, lane = tid & 63;
    int kstep = f >> 2, cb = f & 3;
    int q0 = kstep * 32 + (lane >> 4) * 8;
    int col = cb * 16 + (lane & 15);
    unsigned short* dst = wf + (size_t)tid * 8;
#pragma unroll
    for (int j = 0; j < 8; j++) dst[j] = f2bf(W[(q0 + j) * 64 + col]);
}

// ---------------- phase 3: aggregation ----------------
// one wave per node; lane = channel ci
__global__ __launch_bounds__(64) void k_agg(const unsigned short* __restrict__ xb,
                                            const int* __restrict__ colA,
                                            const float* __restrict__ ff,
                                            const int* __restrict__ sorted,
                                            const int* __restrict__ starts,
                                            unsigned short* __restrict__ agg, int Nn) {
    int node = blockIdx.x;
    int lane = threadIdx.x;
    int s = starts[node], e = starts[node + 1];
    float acc[KB] = {0, 0, 0, 0, 0, 0, 0, 0, 0};
#pragma unroll 4
    for (int p = s; p < e; ++p) {
        int ej = sorted[p];                    // uniform across wave
        int cj = colA[ej];
        cj = (cj < 0) ? 0 : ((cj >= Nn) ? Nn - 1 : cj);
        float xv = bf2f(xb[cj * CH + lane]);   // coalesced 128B gather
        const float* fp = ff + (size_t)ej * KB;
#pragma unroll
        for (int k = 0; k < KB; k++) acc[k] = fmaf(fp[k], xv, acc[k]);
    }
    size_t b = (size_t)node * (KB * CH) + lane;
#pragma unroll
    for (int k = 0; k < KB; k++) agg[b + k * CH] = f2bf(acc[k]);
}

// ---------------- phase 4: GEMM out = AGG @ W ----------------
// block = 4 waves, each wave: 16 rows x 64 cols. K=576 in two halves of 9 ksteps
// (W fragments staged in LDS 36,864B per half to stay under the 64KB static limit).
__global__ __launch_bounds__(256) void k_gemm(const unsigned short* __restrict__ agg,
                                              const unsigned short* __restrict__ wf,
                                              float* __restrict__ out, int Nn) {
    __shared__ unsigned short lw[18432];  // 36 frags * 64 lanes * 8 bf16
    int t = threadIdx.x;
    int w = t >> 6, lane = t & 63;
    int m0 = blockIdx.x * 64 + w * 16;
    bool active = (m0 < Nn);
    int row = m0 + (lane & 15);
    if (!active) row = 0;
    const unsigned short* abase = agg + (size_t)row * 576 + (lane >> 4) * 8;

    f32x4 acc0 = {0, 0, 0, 0}, acc1 = {0, 0, 0, 0}, acc2 = {0, 0, 0, 0}, acc3 = {0, 0, 0, 0};

    for (int half = 0; half < 2; ++half) {
        __syncthreads();
        {
            const bf16x8* src = (const bf16x8*)wf + half * 2304;
            bf16x8* dst = (bf16x8*)lw;
#pragma unroll
            for (int i = t; i < 2304; i += 256) dst[i] = src[i];
        }
        __syncthreads();
        if (active) {
#pragma unroll
            for (int ks2 = 0; ks2 < 9; ++ks2) {
                int ks = half * 9 + ks2;
                bf16x8 a = *(const bf16x8*)(abase + (size_t)ks * 32);
                const bf16x8* bl = (const bf16x8*)lw + ks2 * 256 + lane;
                acc0 = __builtin_amdgcn_mfma_f32_16x16x32_bf16(a, bl[0],   acc0, 0, 0, 0);
                acc1 = __builtin_amdgcn_mfma_f32_16x16x32_bf16(a, bl[64],  acc1, 0, 0, 0);
                acc2 = __builtin_amdgcn_mfma_f32_16x16x32_bf16(a, bl[128], acc2, 0, 0, 0);
                acc3 = __builtin_amdgcn_mfma_f32_16x16x32_bf16(a, bl[192], acc3, 0, 0, 0);
            }
        }
    }
    if (active) {
        int crow = (lane >> 4) * 4;
        int ccol = lane & 15;
        float* ob = out + (size_t)m0 * CH;
#pragma unroll
        for (int r = 0; r < 4; r++) {
            ob[(crow + r) * CH + ccol]      = acc0[r];
            ob[(crow + r) * CH + 16 + ccol] = acc1[r];
            ob[(crow + r) * CH + 32 + ccol] = acc2[r];
            ob[(crow + r) * CH + 48 + ccol] = acc3[r];
        }
    }
}

extern "C" void kernel_launch(void* const* d_in, const int* in_sizes, int n_in,
                              void* d_out, int out_size, void* d_ws, size_t ws_size,
                              hipStream_t stream) {
    const float* x   = (const float*)d_in[0];
    const int*   nbr = (const int*)d_in[1];
    const float* ff  = (const float*)d_in[2];
    const float* W   = (const float*)d_in[3];
    float* out = (float*)d_out;

    int Nn = in_sizes[0] / CH;   // 50000
    int E  = in_sizes[1] / 2;    // 1600000
    const int* row = nbr;
    const int* col = nbr + E;

    // workspace carve (512B aligned slots), total ~71.3 MB
    char* p = (char*)d_ws;
    auto alloc = [&](size_t bytes) -> void* {
        void* r = (void*)p;
        p += (bytes + 511) & ~(size_t)511;
        return r;
    };
    int* cnt    = (int*)alloc((size_t)Nn * 4);
    int* loc    = (int*)alloc((size_t)Nn * 4);
    int* csum   = (int*)alloc(1024);
    int* coff   = (int*)alloc(1024);
    int* starts = (int*)alloc((size_t)(Nn + 1) * 4);
    int* cur    = (int*)alloc((size_t)Nn * 4);
    int* sorted = (int*)alloc((size_t)E * 4);
    unsigned short* xb  = (unsigned short*)alloc((size_t)Nn * CH * 2);
    unsigned short* wf  = (unsigned short*)alloc(72 * 64 * 8 * 2);
    unsigned short* agg = (unsigned short*)alloc((size_t)Nn * (KB * CH) * 2);

    hipMemsetAsync(cnt, 0, (size_t)Nn * 4, stream);

    k_hist<<<2048, 256, 0, stream>>>(row, cnt, E, Nn);

    int nch = (Nn + 255) / 256;  // 196
    k_scan1<<<nch, 256, 0, stream>>>(cnt, loc, csum, Nn);
    k_scan2<<<1, 256, 0, stream>>>(csum, coff, nch);
    k_scan3<<<nch, 256, 0, stream>>>(loc, coff, starts, cur, Nn, E);

    k_scatter<<<2048, 256, 0, stream>>>(row, cur, sorted, E, Nn);

    k_xconv<<<2048, 256, 0, stream>>>(x, xb, Nn * CH);
    k_wprep<<<18, 256, 0, stream>>>(W, wf);

    k_agg<<<Nn, 64, 0, stream>>>(xb, col, ff, sorted, starts, agg, Nn);

    k_gemm<<<(Nn + 63) / 64, 256, 0, stream>>>(agg, wf, out, Nn);
}

// Round 4
// 398.666 us; speedup vs baseline: 1.2777x; 1.2777x over previous
//
#include <hip/hip_runtime.h>

// meshLayer: out[n] = sum_{e: row[e]==n} sum_k ff[e,k] * (x[col[e]] @ W[k])
// Pipeline: CSR build -> scatter 32B edge records (col + ff as bf16) into CSR
// order -> fused kernel: per-16-node tile, aggregate AGG[n, k*64+ci] streaming
// records (only random access = x row gather), stage in LDS, MFMA with W.

#define CH 64
#define KB 9
#define LROW 584  // 576 + 8 pad elements; row stride 1168 B (16B aligned, spreads banks)

using f32x4  = __attribute__((ext_vector_type(4))) float;
using bf16x8 = __attribute__((ext_vector_type(8))) short;

__device__ __forceinline__ float bf2f(unsigned short u) {
    unsigned v = ((unsigned)u) << 16;
    return __builtin_bit_cast(float, v);
}
__device__ __forceinline__ unsigned short f2bf(float f) {
    unsigned x = __builtin_bit_cast(unsigned, f);
    unsigned r = (x + 0x7FFFu + ((x >> 16) & 1u)) >> 16;   // RNE
    return (unsigned short)r;
}
__device__ __forceinline__ float lo16(unsigned v) {        // bf16 in low half
    return __builtin_bit_cast(float, v << 16);
}
__device__ __forceinline__ float hi16(unsigned v) {        // bf16 in high half
    return __builtin_bit_cast(float, v & 0xFFFF0000u);
}
__device__ __forceinline__ unsigned pk(float a, float b) {
    return (unsigned)f2bf(a) | ((unsigned)f2bf(b) << 16);
}

// ---------------- CSR build ----------------

__global__ void k_hist_xconv(const int* __restrict__ row, int* __restrict__ cnt,
                             const float* __restrict__ x, unsigned short* __restrict__ xb,
                             int E, int Nn) {
    int stride = gridDim.x * blockDim.x;
    int gid = blockIdx.x * blockDim.x + threadIdx.x;
    for (int e = gid; e < E; e += stride) {
        int r = row[e];
        r = (r < 0) ? 0 : ((r >= Nn) ? Nn - 1 : r);
        atomicAdd(&cnt[r], 1);
    }
    int M = Nn * CH;
    for (int i = gid; i < M; i += stride) xb[i] = f2bf(x[i]);
}

__global__ void k_scan1(const int* __restrict__ cnt, int* __restrict__ loc,
                        int* __restrict__ csum, int Nn) {
    int t = threadIdx.x, lane = t & 63, w = t >> 6;
    int i = blockIdx.x * 256 + t;
    int v = (i < Nn) ? cnt[i] : 0;
    int x = v;
#pragma unroll
    for (int off = 1; off < 64; off <<= 1) {
        int y = __shfl_up(x, off);
        if (lane >= off) x += y;
    }
    __shared__ int ws[4], wo[4];
    if (lane == 63) ws[w] = x;
    __syncthreads();
    if (t == 0) {
        int s = 0;
        for (int j = 0; j < 4; j++) { int tv = ws[j]; wo[j] = s; s += tv; }
    }
    __syncthreads();
    x += wo[w];
    if (i < Nn) loc[i] = x - v;
    if (t == 255) csum[blockIdx.x] = x;
}

__global__ void k_scan2(const int* __restrict__ csum, int* __restrict__ coff, int nch) {
    int t = threadIdx.x, lane = t & 63, w = t >> 6;
    int v = (t < nch) ? csum[t] : 0;
    int x = v;
#pragma unroll
    for (int off = 1; off < 64; off <<= 1) {
        int y = __shfl_up(x, off);
        if (lane >= off) x += y;
    }
    __shared__ int ws[4], wo[4];
    if (lane == 63) ws[w] = x;
    __syncthreads();
    if (t == 0) {
        int s = 0;
        for (int j = 0; j < 4; j++) { int tv = ws[j]; wo[j] = s; s += tv; }
    }
    __syncthreads();
    x += wo[w];
    if (t < nch) coff[t] = x - v;
}

// scan3 + W->bf16 fragment prep fused (blocks 0..17 also do wprep work)
__global__ void k_scan3_wprep(const int* __restrict__ loc, const int* __restrict__ coff,
                              int* __restrict__ starts, int* __restrict__ cur,
                              const float* __restrict__ W, unsigned short* __restrict__ wfb,
                              int Nn, int E) {
    int i = blockIdx.x * 256 + threadIdx.x;
    if (i < Nn) {
        int st = loc[i] + coff[i >> 8];
        starts[i] = st;
        cur[i] = st;
    }
    if (i == 0) starts[Nn] = E;
    if (i < 72 * 64) {
        int f = i >> 6, lane = i & 63;
        int kstep = f >> 2, cb = f & 3;
        int q0 = kstep * 32 + (lane >> 4) * 8;
        int c = cb * 16 + (lane & 15);
        unsigned short* dst = wfb + (size_t)i * 8;
#pragma unroll
        for (int j = 0; j < 8; j++) dst[j] = f2bf(W[(q0 + j) * CH + c]);
    }
}

// scatter: build CSR-ordered 32B records {col, ff[9] bf16}
__global__ void k_scatter(const int* __restrict__ row, const int* __restrict__ col,
                          const float* __restrict__ ff, int* __restrict__ cur,
                          unsigned* __restrict__ rec, int E, int Nn) {
    int stride = gridDim.x * blockDim.x;
    for (int e = blockIdx.x * blockDim.x + threadIdx.x; e < E; e += stride) {
        int r = row[e];
        r = (r < 0) ? 0 : ((r >= Nn) ? Nn - 1 : r);
        int c = col[e];
        c = (c < 0) ? 0 : ((c >= Nn) ? Nn - 1 : c);
        const float* fp = ff + (size_t)e * KB;
        unsigned d1 = pk(fp[0], fp[1]);
        unsigned d2 = pk(fp[2], fp[3]);
        unsigned d3 = pk(fp[4], fp[5]);
        unsigned d4 = pk(fp[6], fp[7]);
        unsigned d5 = (unsigned)f2bf(fp[8]);
        int pos = atomicAdd(&cur[r], 1);
        uint4* dst = (uint4*)(rec + (size_t)pos * 8);
        uint4 a, b;
        a.x = (unsigned)c; a.y = d1; a.z = d2; a.w = d3;
        b.x = d4; b.y = d5; b.z = 0u; b.w = 0u;
        dst[0] = a;
        dst[1] = b;
    }
}

// ---------------- fused aggregate + GEMM ----------------
// block = 256 threads = 4 waves, one 16-node tile.
// Wave w aggregates nodes n0+w*4 .. +4 into LDS A-tile rows (bf16), then
// computes the 16x16 output quadrant for columns w*16..w*16+16 via MFMA.

#define FMA9(ra, rb, xv)                                   \
    acc0 = fmaf(lo16((ra).y), (xv), acc0);                 \
    acc1 = fmaf(hi16((ra).y), (xv), acc1);                 \
    acc2 = fmaf(lo16((ra).z), (xv), acc2);                 \
    acc3 = fmaf(hi16((ra).z), (xv), acc3);                 \
    acc4 = fmaf(lo16((ra).w), (xv), acc4);                 \
    acc5 = fmaf(hi16((ra).w), (xv), acc5);                 \
    acc6 = fmaf(lo16((rb).x), (xv), acc6);                 \
    acc7 = fmaf(hi16((rb).x), (xv), acc7);                 \
    acc8 = fmaf(lo16((rb).y), (xv), acc8);

__global__ __launch_bounds__(256) void k_fused(const unsigned short* __restrict__ xb,
                                               const unsigned* __restrict__ rec,
                                               const int* __restrict__ starts,
                                               const unsigned short* __restrict__ wfb,
                                               float* __restrict__ out, int Nn) {
    __shared__ unsigned short A[16 * LROW];
    int t = threadIdx.x, w = t >> 6, lane = t & 63;
    int n0 = blockIdx.x * 16;

    for (int j = 0; j < 4; ++j) {
        int node = n0 + w * 4 + j;
        float acc0 = 0, acc1 = 0, acc2 = 0, acc3 = 0, acc4 = 0,
              acc5 = 0, acc6 = 0, acc7 = 0, acc8 = 0;
        if (node < Nn) {
            int s = starts[node], e = starts[node + 1];
            const uint4* r4 = (const uint4*)rec + (size_t)s * 2;
            int m = e - s, p = 0;
            for (; p + 4 <= m; p += 4) {
                uint4 ra0 = r4[p * 2 + 0], rb0 = r4[p * 2 + 1];
                uint4 ra1 = r4[p * 2 + 2], rb1 = r4[p * 2 + 3];
                uint4 ra2 = r4[p * 2 + 4], rb2 = r4[p * 2 + 5];
                uint4 ra3 = r4[p * 2 + 6], rb3 = r4[p * 2 + 7];
                float x0 = bf2f(xb[ra0.x * CH + lane]);
                float x1 = bf2f(xb[ra1.x * CH + lane]);
                float x2 = bf2f(xb[ra2.x * CH + lane]);
                float x3 = bf2f(xb[ra3.x * CH + lane]);
                FMA9(ra0, rb0, x0)
                FMA9(ra1, rb1, x1)
                FMA9(ra2, rb2, x2)
                FMA9(ra3, rb3, x3)
            }
            for (; p < m; ++p) {
                uint4 ra = r4[p * 2 + 0], rb = r4[p * 2 + 1];
                float xv = bf2f(xb[ra.x * CH + lane]);
                FMA9(ra, rb, xv)
            }
        }
        unsigned short* dst = A + (w * 4 + j) * LROW + lane;
        dst[0 * 64] = f2bf(acc0); dst[1 * 64] = f2bf(acc1); dst[2 * 64] = f2bf(acc2);
        dst[3 * 64] = f2bf(acc3); dst[4 * 64] = f2bf(acc4); dst[5 * 64] = f2bf(acc5);
        dst[6 * 64] = f2bf(acc6); dst[7 * 64] = f2bf(acc7); dst[8 * 64] = f2bf(acc8);
    }
    __syncthreads();

    f32x4 C = {0, 0, 0, 0};
    int arow = lane & 15, g = lane >> 4;
    const unsigned short* ab = A + arow * LROW + g * 8;
    const bf16x8* wv = (const bf16x8*)wfb;
#pragma unroll
    for (int ks = 0; ks < 18; ++ks) {
        bf16x8 a = *(const bf16x8*)(ab + ks * 32);
        bf16x8 b = wv[(ks * 4 + w) * 64 + lane];
        C = __builtin_amdgcn_mfma_f32_16x16x32_bf16(a, b, C, 0, 0, 0);
    }
    float* ob = out + (size_t)n0 * CH + w * 16 + (lane & 15);
#pragma unroll
    for (int r = 0; r < 4; ++r) {
        int orow = g * 4 + r;
        if (n0 + orow < Nn) ob[orow * CH] = C[r];
    }
}

extern "C" void kernel_launch(void* const* d_in, const int* in_sizes, int n_in,
                              void* d_out, int out_size, void* d_ws, size_t ws_size,
                              hipStream_t stream) {
    const float* x   = (const float*)d_in[0];
    const int*   nbr = (const int*)d_in[1];
    const float* ff  = (const float*)d_in[2];
    const float* W   = (const float*)d_in[3];
    float* out = (float*)d_out;

    int Nn = in_sizes[0] / CH;   // 50000
    int E  = in_sizes[1] / 2;    // 1600000
    const int* row = nbr;
    const int* col = nbr + E;

    char* p = (char*)d_ws;
    auto alloc = [&](size_t bytes) -> void* {
        void* r = (void*)p;
        p += (bytes + 511) & ~(size_t)511;
        return r;
    };
    int* cnt    = (int*)alloc((size_t)Nn * 4);
    int* loc    = (int*)alloc((size_t)Nn * 4);
    int* csum   = (int*)alloc(1024);
    int* coff   = (int*)alloc(1024);
    int* starts = (int*)alloc((size_t)(Nn + 1) * 4);
    int* cur    = (int*)alloc((size_t)Nn * 4);
    unsigned* rec = (unsigned*)alloc((size_t)E * 32);            // 51.2 MB
    unsigned short* xb  = (unsigned short*)alloc((size_t)Nn * CH * 2);
    unsigned short* wfb = (unsigned short*)alloc(72 * 64 * 8 * 2);

    hipMemsetAsync(cnt, 0, (size_t)Nn * 4, stream);

    k_hist_xconv<<<2048, 256, 0, stream>>>(row, cnt, x, xb, E, Nn);

    int nch = (Nn + 255) / 256;  // 196
    k_scan1<<<nch, 256, 0, stream>>>(cnt, loc, csum, Nn);
    k_scan2<<<1, 256, 0, stream>>>(csum, coff, nch);
    k_scan3_wprep<<<nch, 256, 0, stream>>>(loc, coff, starts, cur, W, wfb, Nn, E);

    k_scatter<<<2048, 256, 0, stream>>>(row, col, ff, cur, rec, E, Nn);

    k_fused<<<(Nn + 15) / 16, 256, 0, stream>>>(xb, rec, starts, wfb, out, Nn);
}